// Round 9
// baseline (319.751 us; speedup 1.0000x reference)
//
#include <hip/hip_runtime.h>

typedef unsigned short u16;
typedef __bf16 bf16x8 __attribute__((ext_vector_type(8)));
typedef __bf16 bf16x4 __attribute__((ext_vector_type(4)));
typedef float floatx4 __attribute__((ext_vector_type(4)));
typedef u16 u16x4 __attribute__((ext_vector_type(4)));

#define MEG ((size_t)(1u << 20))

__device__ __forceinline__ u16 f2bf(float f) {
  unsigned int u = __float_as_uint(f);
  u += 0x7fffu + ((u >> 16) & 1u);   // round-to-nearest-even
  return (u16)(u >> 16);
}

// async global->LDS, 16B per lane; LDS dest = wave-uniform base + lane*16
__device__ __forceinline__ void load_lds16(const u16* g, u16* l) {
  __builtin_amdgcn_global_load_lds((const __attribute__((address_space(1))) unsigned int*)g,
                                   (__attribute__((address_space(3))) unsigned int*)l,
                                   16, 0, 0);
}

// ---------------- fp32 -> bf16 conversion of the 7 fp32 inputs ----------------
// layout (elements): [q 4M][k 4M][v 4M][Wq 1M][Wk 1M][Wv 1M][Wo 1M] = 16M
__global__ __launch_bounds__(256) void cvt7(
    const float* __restrict__ s0, const float* __restrict__ s1,
    const float* __restrict__ s2, const float* __restrict__ s3,
    const float* __restrict__ s4, const float* __restrict__ s5,
    const float* __restrict__ s6, u16* __restrict__ dst)
{
  size_t e = ((size_t)blockIdx.x * 256 + threadIdx.x) * 4;
  unsigned m = (unsigned)(e >> 20);
  const float* s; size_t off;
  if (m < 4)       { s = s0; off = e; }
  else if (m < 8)  { s = s1; off = e - 4 * MEG; }
  else if (m < 12) { s = s2; off = e - 8 * MEG; }
  else if (m < 13) { s = s3; off = e - 12 * MEG; }
  else if (m < 14) { s = s4; off = e - 13 * MEG; }
  else if (m < 15) { s = s5; off = e - 14 * MEG; }
  else             { s = s6; off = e - 15 * MEG; }
  float4 f = *reinterpret_cast<const float4*>(s + off);
  u16x4 o;
  o.x = f2bf(f.x); o.y = f2bf(f.y); o.z = f2bf(f.z); o.w = f2bf(f.w);
  *reinterpret_cast<u16x4*>(dst + e) = o;
}

// ---------------- generic C = A * B^T (+bias) bf16 MFMA GEMM, BK=64 ----------
// A: MxK bf16 row-major, B: NxK bf16 row-major, C: MxN (bf16 or fp32)
// Tile (IT*32) x 128, 256 threads = 4 waves (2x2); IT=4 -> 128x128, IT=2 -> 64x128.
// xor-chunk-swizzled LDS; SOFTWARE-PIPELINED K-loop: loads for it+1 issued
// after the read-barrier, in flight across the MFMA phase (both barriers have
// vmcnt==0 at drain time -> zero-cost).
// VT: blockIdx.z==2 writes the transposed-per-head layout Vt[bh][d][l] instead.
template<int IT, bool OUT_BF16, bool ADD_BIAS, bool VT>
__global__ __launch_bounds__(256) void gemm_bt(
    const u16* __restrict__ Abase, const u16* __restrict__ Bbase,
    const float* __restrict__ bias, void* __restrict__ Cbase,
    u16* __restrict__ VtB,
    int M, int N, int K, long zA, long zB, long zC)
{
  __shared__ __align__(16) u16 As[IT * 32 * 64];
  __shared__ __align__(16) u16 Bs[128 * 64];
  const int tid = threadIdx.x;
  const int w = tid >> 6, ln = tid & 63;
  const int lm = ln & 15, lq = ln >> 4;
  const int wm = w >> 1, wn = w & 1;
  const long m0 = (long)blockIdx.y * (IT * 32), n0 = (long)blockIdx.x * 128;
  const u16* A = Abase + (size_t)blockIdx.z * (size_t)zA;
  const u16* B = Bbase + (size_t)blockIdx.z * (size_t)zB;

  // staging source pointers (row r0 = tid>>3, chunk kc = (tid&7)^(r0&7))
  const int r0 = tid >> 3;
  const int kc = (tid & 7) ^ (r0 & 7);
  const u16* gA = A + (m0 + r0) * (long)K + kc * 8;
  const u16* gB = B + (n0 + r0) * (long)K + kc * 8;
  const long rstep = 32L * K;

  // loop-invariant fragment base pointers
  const int sl0 = (lq ^ (lm & 7)) * 8;
  const int sl1 = ((4 + lq) ^ (lm & 7)) * 8;
  const u16* ab0 = &As[(wm * (IT * 16) + lm) * 64 + sl0];
  const u16* ab1 = &As[(wm * (IT * 16) + lm) * 64 + sl1];
  const u16* bb0 = &Bs[(wn * 64 + lm) * 64 + sl0];
  const u16* bb1 = &Bs[(wn * 64 + lm) * 64 + sl1];

  const floatx4 z4 = {0.f, 0.f, 0.f, 0.f};
  floatx4 acc[IT][4];
#pragma unroll
  for (int i = 0; i < IT; ++i)
#pragma unroll
    for (int j = 0; j < 4; ++j) acc[i][j] = z4;

  // prologue: stage tile 0
#pragma unroll
  for (int t = 0; t < IT; ++t)
    load_lds16(gA + t * rstep, &As[(t * 256 + w * 64) * 8]);
#pragma unroll
  for (int t = 0; t < 4; ++t)
    load_lds16(gB + t * rstep, &Bs[(t * 256 + w * 64) * 8]);
  gA += 64; gB += 64;

  for (int k0 = 0; k0 < K; k0 += 64) {
    __builtin_amdgcn_s_waitcnt(0);   // own staging loads complete
    __syncthreads();                 // everyone's complete -> tile coherent
    bf16x8 af[IT][2], bfr[4][2];
#pragma unroll
    for (int i = 0; i < IT; ++i) {
      af[i][0] = *reinterpret_cast<const bf16x8*>(ab0 + i * 1024);
      af[i][1] = *reinterpret_cast<const bf16x8*>(ab1 + i * 1024);
    }
#pragma unroll
    for (int j = 0; j < 4; ++j) {
      bfr[j][0] = *reinterpret_cast<const bf16x8*>(bb0 + j * 1024);
      bfr[j][1] = *reinterpret_cast<const bf16x8*>(bb1 + j * 1024);
    }
    __syncthreads();                 // all waves done reading -> safe to overwrite
    if (k0 + 64 < K) {
#pragma unroll
      for (int t = 0; t < IT; ++t)
        load_lds16(gA + t * rstep, &As[(t * 256 + w * 64) * 8]);
#pragma unroll
      for (int t = 0; t < 4; ++t)
        load_lds16(gB + t * rstep, &Bs[(t * 256 + w * 64) * 8]);
      gA += 64; gB += 64;
    }
#pragma unroll
    for (int i = 0; i < IT; ++i)
#pragma unroll
      for (int j = 0; j < 4; ++j) {
        acc[i][j] = __builtin_amdgcn_mfma_f32_16x16x32_bf16(af[i][0], bfr[j][0], acc[i][j], 0, 0, 0);
        acc[i][j] = __builtin_amdgcn_mfma_f32_16x16x32_bf16(af[i][1], bfr[j][1], acc[i][j], 0, 0, 0);
      }
  }

  if (VT && blockIdx.z == 2) {
    // write V^T per head: Vt[(b*16+h)][d][l]; r=0..3 -> consecutive l -> one b64
#pragma unroll
    for (int i = 0; i < IT; ++i) {
      long row = m0 + wm * (IT * 16) + i * 16 + lq * 4;   // row = b*2048 + l
      int bq = (int)(row >> 11);
      int l  = (int)(row & 2047);
#pragma unroll
      for (int j = 0; j < 4; ++j) {
        long col = n0 + wn * 64 + j * 16 + lm;            // col = h*64 + d
        int hh = (int)(col >> 6), dd = (int)(col & 63);
        u16x4 o;
        o.x = f2bf(acc[i][j][0]); o.y = f2bf(acc[i][j][1]);
        o.z = f2bf(acc[i][j][2]); o.w = f2bf(acc[i][j][3]);
        *reinterpret_cast<u16x4*>(&VtB[((size_t)(bq * 16 + hh)) * 131072 +
                                       (size_t)dd * 2048 + l]) = o;
      }
    }
    return;
  }

#pragma unroll
  for (int i = 0; i < IT; ++i) {
    long row = m0 + wm * (IT * 16) + i * 16 + lq * 4;
#pragma unroll
    for (int j = 0; j < 4; ++j) {
      long col = n0 + wn * 64 + j * 16 + lm;
#pragma unroll
      for (int r = 0; r < 4; ++r) {
        float v = acc[i][j][r];
        if (ADD_BIAS) v += bias[col];
        size_t idx = (size_t)(row + r) * (size_t)N + (size_t)col;
        if (OUT_BF16) (((u16*)Cbase) + (size_t)blockIdx.z * (size_t)zC)[idx] = f2bf(v);
        else ((float*)Cbase)[idx] = v;
      }
    }
  }
}

// ---------------- flash attention, K-split=2, pipelined K-loop ---------------
// grid (16 q-tiles of 128, 32 bh, 2 K-halves) = 1024 blocks, 4 waves,
// 32 q-rows/wave (2 subtiles of 16), K-tile 64, 16 iters per block.
// Ps shared across m-subtiles (same-wave DS ordering) -> 26 KB LDS.
// Writes UN-normalized O (bf16) + fp32 psum partials; combine_norm finishes.
__global__ __launch_bounds__(256, 4) void attn_kernel(
    const u16* __restrict__ Qp, const u16* __restrict__ Kp,
    const u16* __restrict__ Vt, const int* __restrict__ mask,
    u16* __restrict__ OpBase, float* __restrict__ psAB)
{
  __shared__ __align__(16) u16 Ks[64 * 64];       // 8 KB, slot = c ^ (key&7)
  __shared__ __align__(16) u16 Vts[64 * 64];      // 8 KB, slot = c ^ (d&7)
  __shared__ __align__(16) u16 Ps[4 * 16 * 64];   // 8 KB, per-wave (m-shared)
  __shared__ __align__(16) u16 mball[1024];       // 2 KB mask bias as bf16 (0/-inf)

  const int tid = threadIdx.x;
  const int w = tid >> 6, ln = tid & 63;
  const int lm = ln & 15, lq = ln >> 4;
  const int bh = blockIdx.y, b = bh >> 4, h = bh & 15;
  const int q0 = blockIdx.x * 128;
  const int kz = blockIdx.z;

  const u16* Qh = Qp + (size_t)b * 2048 * 1024 + h * 64;
  const u16* Kh = Kp + (size_t)b * 2048 * 1024 + (size_t)kz * 1024 * 1024 + h * 64;
  const u16* Vth = Vt + (size_t)bh * 64 * 2048 + kz * 1024;
  u16* Op = OpBase + (size_t)kz * 8 * MEG;
  float* psZ = psAB + (size_t)kz * 65536;

  // mask bias staged once (iter-0 barrier covers visibility)
  const int* mrowp = mask + b * 2048 + kz * 1024;
#pragma unroll
  for (int t = 0; t < 4; ++t) {
    int i = t * 256 + tid;
    mball[i] = (mrowp[i] != 0) ? (u16)0 : (u16)0xFF80;   // 0.0 or -inf (bf16)
  }

  // persistent Q fragments (B-operand for S^T), 2 q-subtiles
  bf16x8 qf[2][2];
#pragma unroll
  for (int m = 0; m < 2; ++m) {
    int qrow = q0 + w * 32 + m * 16 + lm;
    qf[m][0] = *reinterpret_cast<const bf16x8*>(Qh + (size_t)qrow * 1024 + lq * 8);
    qf[m][1] = *reinterpret_cast<const bf16x8*>(Qh + (size_t)qrow * 1024 + 32 + lq * 8);
  }

  // loop-invariant LDS pointers
  const int sl0 = (lq ^ (lm & 7)) * 8;
  const int sl1 = ((4 + lq) ^ (lm & 7)) * 8;
  const u16* kb0 = &Ks[lm * 64 + sl0];
  const u16* kb1 = &Ks[lm * 64 + sl1];
  const u16* vb0 = &Vts[lm * 64 + sl0];
  const u16* vb1 = &Vts[lm * 64 + sl1];
  u16* Pw = &Ps[w * 1024];
  u16* pwr[4];
#pragma unroll
  for (int n = 0; n < 4; ++n) pwr[n] = &Pw[lm * 64 + (((4 * n + lq) ^ lm) * 4)];
  const u16* prd[4];
#pragma unroll
  for (int t = 0; t < 4; ++t)
    prd[t] = &Pw[lm * 64 + (((8 * (t >> 1) + 2 * lq + (t & 1)) ^ lm) * 4)];
  const u16* mbi = mball + lq * 4;

  // staging source running pointers (row r0 = tid>>3, chunk kc = (tid&7)^(r0&7))
  const int r0 = tid >> 3;
  const int kc = (tid & 7) ^ (r0 & 7);
  const u16* gK0 = Kh + (size_t)r0 * 1024 + kc * 8;
  const u16* gK1 = gK0 + 32 * 1024;
  const u16* gV0 = Vth + (size_t)r0 * 2048 + kc * 8;
  const u16* gV1 = gV0 + 32 * 2048;

  const floatx4 z4 = {0.f, 0.f, 0.f, 0.f};
  floatx4 O[2][4];
#pragma unroll
  for (int m = 0; m < 2; ++m)
#pragma unroll
    for (int j = 0; j < 4; ++j) O[m][j] = z4;
  float psum[2] = {0.f, 0.f};
  const float SCL = 0.18033688011112042f;  // log2(e) / sqrt(64)

  // prologue: stage tile 0
  load_lds16(gK0, &Ks[(w * 64) * 8]);
  load_lds16(gK1, &Ks[(256 + w * 64) * 8]);
  load_lds16(gV0, &Vts[(w * 64) * 8]);
  load_lds16(gV1, &Vts[(256 + w * 64) * 8]);
  gK0 += 64 * 1024; gK1 += 64 * 1024; gV0 += 64; gV1 += 64;

  for (int it = 0; it < 16; ++it) {
    __builtin_amdgcn_s_waitcnt(0);   // own staging loads complete
    __syncthreads();                 // everyone's complete -> tile coherent

    // all tile-dependent reads -> registers
    bf16x8 kf[4][2], vf[4][2];
#pragma unroll
    for (int n = 0; n < 4; ++n) {
      kf[n][0] = *reinterpret_cast<const bf16x8*>(kb0 + n * 1024);
      kf[n][1] = *reinterpret_cast<const bf16x8*>(kb1 + n * 1024);
    }
#pragma unroll
    for (int j = 0; j < 4; ++j) {
      vf[j][0] = *reinterpret_cast<const bf16x8*>(vb0 + j * 1024);
      vf[j][1] = *reinterpret_cast<const bf16x8*>(vb1 + j * 1024);
    }
    float mb4[4][4];
#pragma unroll
    for (int n = 0; n < 4; ++n) {
      u16x4 mv = *reinterpret_cast<const u16x4*>(mbi + n * 16);
      mb4[n][0] = __uint_as_float((unsigned)mv.x << 16);
      mb4[n][1] = __uint_as_float((unsigned)mv.y << 16);
      mb4[n][2] = __uint_as_float((unsigned)mv.z << 16);
      mb4[n][3] = __uint_as_float((unsigned)mv.w << 16);
    }
    mbi += 64;
    __syncthreads();                 // all waves done reading Ks/Vts

    // prefetch next tile, in flight across the compute phase
    if (it < 15) {
      load_lds16(gK0, &Ks[(w * 64) * 8]);
      load_lds16(gK1, &Ks[(256 + w * 64) * 8]);
      load_lds16(gV0, &Vts[(w * 64) * 8]);
      load_lds16(gV1, &Vts[(256 + w * 64) * 8]);
      gK0 += 64 * 1024; gK1 += 64 * 1024; gV0 += 64; gV1 += 64;
    }

#pragma unroll
    for (int m = 0; m < 2; ++m) {
      // S^T = K_tile * Q^T : D[key_local = lq*4+r][q = lm]
      floatx4 S[4];
#pragma unroll
      for (int n = 0; n < 4; ++n) {
        S[n] = __builtin_amdgcn_mfma_f32_16x16x32_bf16(kf[n][0], qf[m][0], z4, 0, 0, 0);
        S[n] = __builtin_amdgcn_mfma_f32_16x16x32_bf16(kf[n][1], qf[m][1], S[n], 0, 0, 0);
      }

      // p = exp2(S*SCL + maskbias); raw v_exp; pack via +0x8000 + v_perm
#pragma unroll
      for (int n = 0; n < 4; ++n) {
        float p0 = __builtin_amdgcn_exp2f(fmaf(S[n][0], SCL, mb4[n][0]));
        float p1 = __builtin_amdgcn_exp2f(fmaf(S[n][1], SCL, mb4[n][1]));
        float p2 = __builtin_amdgcn_exp2f(fmaf(S[n][2], SCL, mb4[n][2]));
        float p3 = __builtin_amdgcn_exp2f(fmaf(S[n][3], SCL, mb4[n][3]));
        psum[m] += (p0 + p1) + (p2 + p3);
        unsigned u0 = __float_as_uint(p0) + 0x8000u;
        unsigned u1 = __float_as_uint(p1) + 0x8000u;
        unsigned u2 = __float_as_uint(p2) + 0x8000u;
        unsigned u3 = __float_as_uint(p3) + 0x8000u;
        uint2 pk;
        pk.x = __builtin_amdgcn_perm(u1, u0, 0x07060302u);
        pk.y = __builtin_amdgcn_perm(u3, u2, 0x07060302u);
        *reinterpret_cast<uint2*>(pwr[n]) = pk;
      }

      // O += P(16x64) * V(64x64); per-wave Ps, same-wave DS order -> no barrier;
      // m=1's P writes ordered after m=0's P reads (same-wave DS order)
#pragma unroll
      for (int h2 = 0; h2 < 2; ++h2) {
        bf16x4 pa = *reinterpret_cast<const bf16x4*>(prd[2 * h2]);
        bf16x4 pb = *reinterpret_cast<const bf16x4*>(prd[2 * h2 + 1]);
        bf16x8 pf = __builtin_shufflevector(pa, pb, 0, 1, 2, 3, 4, 5, 6, 7);
#pragma unroll
        for (int j = 0; j < 4; ++j)
          O[m][j] = __builtin_amdgcn_mfma_f32_16x16x32_bf16(pf, vf[j][h2], O[m][j], 0, 0, 0);
      }
    }
  }

  // epilogue: reduce psum over lq bits -> per-q total for this K-half;
  // store psum (lanes lq==0, consecutive rows -> coalesced) + raw O (bf16)
#pragma unroll
  for (int m = 0; m < 2; ++m) {
    float s = psum[m];
    s += __shfl_xor(s, 16, 64);
    s += __shfl_xor(s, 32, 64);
    int prow = q0 + w * 32 + m * 16 + lm;
    if (lq == 0) psZ[bh * 2048 + prow] = s;
#pragma unroll
    for (int r = 0; r < 4; ++r) {
      int row = q0 + w * 32 + m * 16 + lq * 4 + r;
      size_t base = ((size_t)b * 2048 + row) * 1024 + h * 64 + lm;
#pragma unroll
      for (int j = 0; j < 4; ++j)
        Op[base + j * 16] = f2bf(O[m][j][r]);
    }
  }
}

// ---------------- combine K-split partials + normalize -> bf16 ctx ----------
__global__ __launch_bounds__(256) void combine_norm(
    const u16* __restrict__ Oa, const u16* __restrict__ Ob,
    const float* __restrict__ psA, const float* __restrict__ psB,
    u16* __restrict__ ctx)
{
  size_t idx = ((size_t)blockIdx.x * 256 + threadIdx.x) * 8;   // over 4M elements
  int q = (int)(idx >> 10);          // b*2048 + l
  int c = (int)(idx & 1023);
  int b = q >> 11, l = q & 2047, h = c >> 6;
  int ql = (b * 16 + h) * 2048 + l;
  float s = psA[ql] + psB[ql];
  float inv = (s > 0.f) ? 1.0f / s : 0.f;   // all-masked row -> 0

  uint4 ua = *reinterpret_cast<const uint4*>(Oa + idx);
  uint4 ub = *reinterpret_cast<const uint4*>(Ob + idx);
  uint4 uo;
  const unsigned* pa = reinterpret_cast<const unsigned*>(&ua);
  const unsigned* pb = reinterpret_cast<const unsigned*>(&ub);
  unsigned* po = reinterpret_cast<unsigned*>(&uo);
#pragma unroll
  for (int i = 0; i < 4; ++i) {
    float alo = __uint_as_float(pa[i] << 16);
    float ahi = __uint_as_float(pa[i] & 0xFFFF0000u);
    float blo = __uint_as_float(pb[i] << 16);
    float bhi = __uint_as_float(pb[i] & 0xFFFF0000u);
    float olo = (alo + blo) * inv;
    float ohi = (ahi + bhi) * inv;
    po[i] = (unsigned)f2bf(olo) | ((unsigned)f2bf(ohi) << 16);
  }
  *reinterpret_cast<uint4*>(ctx + idx) = uo;
}

// ---------------- host ----------------
extern "C" void kernel_launch(void* const* d_in, const int* in_sizes, int n_in,
                              void* d_out, int out_size, void* d_ws, size_t ws_size,
                              hipStream_t stream) {
  const float* q  = (const float*)d_in[0];
  const float* k  = (const float*)d_in[1];
  const float* v  = (const float*)d_in[2];
  const int*   mk = (const int*)  d_in[3];
  const float* wq = (const float*)d_in[4];
  const float* wk = (const float*)d_in[5];
  const float* wv = (const float*)d_in[6];
  const float* wo = (const float*)d_in[7];
  const float* bo = (const float*)d_in[8];

  u16* ws16 = (u16*)d_ws;
  // element offsets (bf16): Xq=0 Xk=4M Xv=8M | Wq=12M Wk=13M Wv=14M Wo=15M
  // Qp=16M Kp=20M Vt=24M.
  // After proj: Xq/Xv/Wq..Wv are dead -> OpA=0..4M, OpB=8..12M,
  // psums (fp32) at element 12M (512 KB inside Wq..), ctx=4..8M (Xk alias).
  u16* Xq  = ws16;
  u16* Wq  = ws16 + 12 * MEG;
  u16* Wo  = ws16 + 15 * MEG;
  u16* Qp  = ws16 + 16 * MEG;
  u16* Kp  = ws16 + 20 * MEG;
  u16* Vt  = ws16 + 24 * MEG;
  u16* OpA = ws16;             // alias Xq
  u16* OpB = ws16 + 8 * MEG;   // alias Xv
  float* psAB = (float*)(ws16 + 12 * MEG);  // alias Wq (2 x 65536 floats)
  u16* ctx = ws16 + 4 * MEG;   // alias Xk

  cvt7<<<dim3(16384), dim3(256), 0, stream>>>(q, k, v, wq, wk, wv, wo, ws16);

  gemm_bt<4, true, false, true><<<dim3(8, 32, 3), dim3(256), 0, stream>>>(
      Xq, Wq, nullptr, (void*)Qp, Vt, 4096, 1024, 1024,
      (long)(4 * MEG), (long)MEG, (long)(4 * MEG));

  attn_kernel<<<dim3(16, 32, 2), dim3(256), 0, stream>>>(Qp, Kp, Vt, mk, OpA, psAB);

  combine_norm<<<dim3(2048), dim3(256), 0, stream>>>(OpA, OpB, psAB, psAB + 65536, ctx);

  gemm_bt<2, false, true, false><<<dim3(8, 64, 1), dim3(256), 0, stream>>>(
      ctx, Wo, bo, d_out, nullptr, 4096, 1024, 1024, 0, 0, 0);
}

// Round 10
// 232.086 us; speedup vs baseline: 1.3777x; 1.3777x over previous
//
#include <hip/hip_runtime.h>

typedef unsigned short u16;
typedef __bf16 bf16x8 __attribute__((ext_vector_type(8)));
typedef __bf16 bf16x4 __attribute__((ext_vector_type(4)));
typedef float floatx4 __attribute__((ext_vector_type(4)));
typedef u16 u16x4 __attribute__((ext_vector_type(4)));

#define MEG ((size_t)(1u << 20))

__device__ __forceinline__ u16 f2bf(float f) {
  unsigned int u = __float_as_uint(f);
  u += 0x7fffu + ((u >> 16) & 1u);   // round-to-nearest-even
  return (u16)(u >> 16);
}

// async global->LDS, 16B per lane; LDS dest = wave-uniform base + lane*16
__device__ __forceinline__ void load_lds16(const u16* g, u16* l) {
  __builtin_amdgcn_global_load_lds((const __attribute__((address_space(1))) unsigned int*)g,
                                   (__attribute__((address_space(3))) unsigned int*)l,
                                   16, 0, 0);
}

// ---------------- fp32 -> bf16 conversion of the 7 fp32 inputs ----------------
// layout (elements): [q 4M][k 4M][v 4M][Wq 1M][Wk 1M][Wv 1M][Wo 1M] = 16M
__global__ __launch_bounds__(256) void cvt7(
    const float* __restrict__ s0, const float* __restrict__ s1,
    const float* __restrict__ s2, const float* __restrict__ s3,
    const float* __restrict__ s4, const float* __restrict__ s5,
    const float* __restrict__ s6, u16* __restrict__ dst)
{
  size_t e = ((size_t)blockIdx.x * 256 + threadIdx.x) * 4;
  unsigned m = (unsigned)(e >> 20);
  const float* s; size_t off;
  if (m < 4)       { s = s0; off = e; }
  else if (m < 8)  { s = s1; off = e - 4 * MEG; }
  else if (m < 12) { s = s2; off = e - 8 * MEG; }
  else if (m < 13) { s = s3; off = e - 12 * MEG; }
  else if (m < 14) { s = s4; off = e - 13 * MEG; }
  else if (m < 15) { s = s5; off = e - 14 * MEG; }
  else             { s = s6; off = e - 15 * MEG; }
  float4 f = *reinterpret_cast<const float4*>(s + off);
  u16x4 o;
  o.x = f2bf(f.x); o.y = f2bf(f.y); o.z = f2bf(f.z); o.w = f2bf(f.w);
  *reinterpret_cast<u16x4*>(dst + e) = o;
}

// ---------------- generic C = A * B^T (+bias) bf16 MFMA GEMM, BK=64 ----------
// (R8 form — single-buffered; pipelining attempt regressed via spills)
template<int IT, bool OUT_BF16, bool ADD_BIAS, bool VT>
__global__ __launch_bounds__(256) void gemm_bt(
    const u16* __restrict__ Abase, const u16* __restrict__ Bbase,
    const float* __restrict__ bias, void* __restrict__ Cbase,
    u16* __restrict__ VtB,
    int M, int N, int K, long zA, long zB, long zC)
{
  __shared__ __align__(16) u16 As[IT * 32 * 64];
  __shared__ __align__(16) u16 Bs[128 * 64];
  const int tid = threadIdx.x;
  const int w = tid >> 6, ln = tid & 63;
  const int lm = ln & 15, lq = ln >> 4;
  const int wm = w >> 1, wn = w & 1;
  const long m0 = (long)blockIdx.y * (IT * 32), n0 = (long)blockIdx.x * 128;
  const u16* A = Abase + (size_t)blockIdx.z * (size_t)zA;
  const u16* B = Bbase + (size_t)blockIdx.z * (size_t)zB;

  const int r0 = tid >> 3;
  const int kc = (tid & 7) ^ (r0 & 7);
  const u16* gA = A + (m0 + r0) * (long)K + kc * 8;
  const u16* gB = B + (n0 + r0) * (long)K + kc * 8;
  const long rstep = 32L * K;

  const int sl0 = (lq ^ (lm & 7)) * 8;
  const int sl1 = ((4 + lq) ^ (lm & 7)) * 8;
  const u16* ab0 = &As[(wm * (IT * 16) + lm) * 64 + sl0];
  const u16* ab1 = &As[(wm * (IT * 16) + lm) * 64 + sl1];
  const u16* bb0 = &Bs[(wn * 64 + lm) * 64 + sl0];
  const u16* bb1 = &Bs[(wn * 64 + lm) * 64 + sl1];

  const floatx4 z4 = {0.f, 0.f, 0.f, 0.f};
  floatx4 acc[IT][4];
#pragma unroll
  for (int i = 0; i < IT; ++i)
#pragma unroll
    for (int j = 0; j < 4; ++j) acc[i][j] = z4;

  for (int k0 = 0; k0 < K; k0 += 64) {
#pragma unroll
    for (int t = 0; t < IT; ++t)
      load_lds16(gA + t * rstep, &As[(t * 256 + w * 64) * 8]);
#pragma unroll
    for (int t = 0; t < 4; ++t)
      load_lds16(gB + t * rstep, &Bs[(t * 256 + w * 64) * 8]);
    gA += 64; gB += 64;
    __syncthreads();
    bf16x8 af[IT][2], bfr[4][2];
#pragma unroll
    for (int i = 0; i < IT; ++i) {
      af[i][0] = *reinterpret_cast<const bf16x8*>(ab0 + i * 1024);
      af[i][1] = *reinterpret_cast<const bf16x8*>(ab1 + i * 1024);
    }
#pragma unroll
    for (int j = 0; j < 4; ++j) {
      bfr[j][0] = *reinterpret_cast<const bf16x8*>(bb0 + j * 1024);
      bfr[j][1] = *reinterpret_cast<const bf16x8*>(bb1 + j * 1024);
    }
#pragma unroll
    for (int i = 0; i < IT; ++i)
#pragma unroll
      for (int j = 0; j < 4; ++j) {
        acc[i][j] = __builtin_amdgcn_mfma_f32_16x16x32_bf16(af[i][0], bfr[j][0], acc[i][j], 0, 0, 0);
        acc[i][j] = __builtin_amdgcn_mfma_f32_16x16x32_bf16(af[i][1], bfr[j][1], acc[i][j], 0, 0, 0);
      }
    __syncthreads();
  }

  if (VT && blockIdx.z == 2) {
#pragma unroll
    for (int i = 0; i < IT; ++i) {
      long row = m0 + wm * (IT * 16) + i * 16 + lq * 4;   // row = b*2048 + l
      int bq = (int)(row >> 11);
      int l  = (int)(row & 2047);
#pragma unroll
      for (int j = 0; j < 4; ++j) {
        long col = n0 + wn * 64 + j * 16 + lm;            // col = h*64 + d
        int hh = (int)(col >> 6), dd = (int)(col & 63);
        u16x4 o;
        o.x = f2bf(acc[i][j][0]); o.y = f2bf(acc[i][j][1]);
        o.z = f2bf(acc[i][j][2]); o.w = f2bf(acc[i][j][3]);
        *reinterpret_cast<u16x4*>(&VtB[((size_t)(bq * 16 + hh)) * 131072 +
                                       (size_t)dd * 2048 + l]) = o;
      }
    }
    return;
  }

#pragma unroll
  for (int i = 0; i < IT; ++i) {
    long row = m0 + wm * (IT * 16) + i * 16 + lq * 4;
#pragma unroll
    for (int j = 0; j < 4; ++j) {
      long col = n0 + wn * 64 + j * 16 + lm;
#pragma unroll
      for (int r = 0; r < 4; ++r) {
        float v = acc[i][j][r];
        if (ADD_BIAS) v += bias[col];
        size_t idx = (size_t)(row + r) * (size_t)N + (size_t)col;
        if (OUT_BF16) (((u16*)Cbase) + (size_t)blockIdx.z * (size_t)zC)[idx] = f2bf(v);
        else ((float*)Cbase)[idx] = v;
      }
    }
  }
}

// ---------------- flash attention, K-split=2, LDS double-buffered DMA --------
// grid (16 q-tiles of 128, 32 bh, 2 K-halves) = 1024 blocks, 4 waves.
// Per iter: issue DMA into buf[1-cur]; s_waitcnt vmcnt(4) (prev tile done);
// raw s_barrier (no drain); compute from buf[cur] (reads sink into MFMA);
// raw s_barrier (protects buf re-staged next iter). Loads in flight across
// the whole compute phase. 42 KB LDS -> 3 blocks/CU.
__global__ __launch_bounds__(256, 3) void attn_kernel(
    const u16* __restrict__ Qp, const u16* __restrict__ Kp,
    const u16* __restrict__ Vt, const int* __restrict__ mask,
    u16* __restrict__ OpBase, float* __restrict__ psAB)
{
  __shared__ __align__(16) u16 Ks[2][64 * 64];    // 16 KB, slot = c ^ (key&7)
  __shared__ __align__(16) u16 Vts[2][64 * 64];   // 16 KB, slot = c ^ (d&7)
  __shared__ __align__(16) u16 Ps[4 * 16 * 64];   // 8 KB, per-wave (m-shared)
  __shared__ __align__(16) u16 mball[1024];       // 2 KB mask bias as bf16 (0/-inf)

  const int tid = threadIdx.x;
  const int w = tid >> 6, ln = tid & 63;
  const int lm = ln & 15, lq = ln >> 4;
  const int bh = blockIdx.y, b = bh >> 4, h = bh & 15;
  const int q0 = blockIdx.x * 128;
  const int kz = blockIdx.z;

  const u16* Qh = Qp + (size_t)b * 2048 * 1024 + h * 64;
  const u16* Kh = Kp + (size_t)b * 2048 * 1024 + (size_t)kz * 1024 * 1024 + h * 64;
  const u16* Vth = Vt + (size_t)bh * 64 * 2048 + kz * 1024;
  u16* Op = OpBase + (size_t)kz * 8 * MEG;
  float* psZ = psAB + (size_t)kz * 65536;

  // mask bias staged once (prologue __syncthreads covers visibility)
  const int* mrowp = mask + b * 2048 + kz * 1024;
#pragma unroll
  for (int t = 0; t < 4; ++t) {
    int i = t * 256 + tid;
    mball[i] = (mrowp[i] != 0) ? (u16)0 : (u16)0xFF80;   // 0.0 or -inf (bf16)
  }

  // persistent Q fragments (B-operand for S^T), 2 q-subtiles
  bf16x8 qf[2][2];
#pragma unroll
  for (int m = 0; m < 2; ++m) {
    int qrow = q0 + w * 32 + m * 16 + lm;
    qf[m][0] = *reinterpret_cast<const bf16x8*>(Qh + (size_t)qrow * 1024 + lq * 8);
    qf[m][1] = *reinterpret_cast<const bf16x8*>(Qh + (size_t)qrow * 1024 + 32 + lq * 8);
  }

  // loop-invariant LDS offsets (buffer select adds cur*4096)
  const int sl0 = (lq ^ (lm & 7)) * 8;
  const int sl1 = ((4 + lq) ^ (lm & 7)) * 8;
  const int kof0 = lm * 64 + sl0, kof1 = lm * 64 + sl1;
  u16* Pw = &Ps[w * 1024];
  u16* pwr[4];
#pragma unroll
  for (int n = 0; n < 4; ++n) pwr[n] = &Pw[lm * 64 + (((4 * n + lq) ^ lm) * 4)];
  const u16* prd[4];
#pragma unroll
  for (int t = 0; t < 4; ++t)
    prd[t] = &Pw[lm * 64 + (((8 * (t >> 1) + 2 * lq + (t & 1)) ^ lm) * 4)];
  const u16* mbi = mball + lq * 4;

  // staging source running pointers (row r0 = tid>>3, chunk kc = (tid&7)^(r0&7))
  const int r0 = tid >> 3;
  const int kc = (tid & 7) ^ (r0 & 7);
  const u16* gK0 = Kh + (size_t)r0 * 1024 + kc * 8;
  const u16* gK1 = gK0 + 32 * 1024;
  const u16* gV0 = Vth + (size_t)r0 * 2048 + kc * 8;
  const u16* gV1 = gV0 + 32 * 2048;

  const floatx4 z4 = {0.f, 0.f, 0.f, 0.f};
  floatx4 O[2][4];
#pragma unroll
  for (int m = 0; m < 2; ++m)
#pragma unroll
    for (int j = 0; j < 4; ++j) O[m][j] = z4;
  float psum[2] = {0.f, 0.f};
  const float SCL = 0.18033688011112042f;  // log2(e) / sqrt(64)

  // prologue: stage tile 0 into buffer 0; full drain once
  load_lds16(gK0, &Ks[0][w * 512]);
  load_lds16(gK1, &Ks[0][2048 + w * 512]);
  load_lds16(gV0, &Vts[0][w * 512]);
  load_lds16(gV1, &Vts[0][2048 + w * 512]);
  gK0 += 64 * 1024; gK1 += 64 * 1024; gV0 += 64; gV1 += 64;
  __syncthreads();

  for (int it = 0; it < 16; ++it) {
    const int cur = it & 1;
    if (it < 15) {
      const int nxt = cur ^ 1;
      load_lds16(gK0, &Ks[nxt][w * 512]);
      load_lds16(gK1, &Ks[nxt][2048 + w * 512]);
      load_lds16(gV0, &Vts[nxt][w * 512]);
      load_lds16(gV1, &Vts[nxt][2048 + w * 512]);
      gK0 += 64 * 1024; gK1 += 64 * 1024; gV0 += 64; gV1 += 64;
      __builtin_amdgcn_s_waitcnt(0x0F74);   // vmcnt<=4: prev tile's 4 loads done
    } else {
      __builtin_amdgcn_s_waitcnt(0x0F70);   // vmcnt<=0
    }
    __builtin_amdgcn_s_barrier();           // tile `cur` coherent; no drain

    const u16* kb = &Ks[cur][0];
    const u16* vb = &Vts[cur][0];

    // mask bias for this K window: bf16<<16 -> f32
    float mb4[4][4];
#pragma unroll
    for (int n = 0; n < 4; ++n) {
      u16x4 mv = *reinterpret_cast<const u16x4*>(mbi + n * 16);
      mb4[n][0] = __uint_as_float((unsigned)mv.x << 16);
      mb4[n][1] = __uint_as_float((unsigned)mv.y << 16);
      mb4[n][2] = __uint_as_float((unsigned)mv.z << 16);
      mb4[n][3] = __uint_as_float((unsigned)mv.w << 16);
    }
    mbi += 64;

    bf16x8 kf[4][2], vf[4][2];
#pragma unroll
    for (int n = 0; n < 4; ++n) {
      kf[n][0] = *reinterpret_cast<const bf16x8*>(kb + n * 1024 + kof0);
      kf[n][1] = *reinterpret_cast<const bf16x8*>(kb + n * 1024 + kof1);
    }
#pragma unroll
    for (int j = 0; j < 4; ++j) {
      vf[j][0] = *reinterpret_cast<const bf16x8*>(vb + j * 1024 + kof0);
      vf[j][1] = *reinterpret_cast<const bf16x8*>(vb + j * 1024 + kof1);
    }

#pragma unroll
    for (int m = 0; m < 2; ++m) {
      // S^T = K_tile * Q^T : D[key_local = lq*4+r][q = lm]
      floatx4 S[4];
#pragma unroll
      for (int n = 0; n < 4; ++n) {
        S[n] = __builtin_amdgcn_mfma_f32_16x16x32_bf16(kf[n][0], qf[m][0], z4, 0, 0, 0);
        S[n] = __builtin_amdgcn_mfma_f32_16x16x32_bf16(kf[n][1], qf[m][1], S[n], 0, 0, 0);
      }

      // p = exp2(S*SCL + maskbias); raw v_exp; pack via +0x8000 + v_perm
#pragma unroll
      for (int n = 0; n < 4; ++n) {
        float p0 = __builtin_amdgcn_exp2f(fmaf(S[n][0], SCL, mb4[n][0]));
        float p1 = __builtin_amdgcn_exp2f(fmaf(S[n][1], SCL, mb4[n][1]));
        float p2 = __builtin_amdgcn_exp2f(fmaf(S[n][2], SCL, mb4[n][2]));
        float p3 = __builtin_amdgcn_exp2f(fmaf(S[n][3], SCL, mb4[n][3]));
        psum[m] += (p0 + p1) + (p2 + p3);
        unsigned u0 = __float_as_uint(p0) + 0x8000u;
        unsigned u1 = __float_as_uint(p1) + 0x8000u;
        unsigned u2 = __float_as_uint(p2) + 0x8000u;
        unsigned u3 = __float_as_uint(p3) + 0x8000u;
        uint2 pk;
        pk.x = __builtin_amdgcn_perm(u1, u0, 0x07060302u);
        pk.y = __builtin_amdgcn_perm(u3, u2, 0x07060302u);
        *reinterpret_cast<uint2*>(pwr[n]) = pk;
      }

      // O += P(16x64) * V(64x64); per-wave Ps, same-wave DS order -> no barrier;
      // m=1's P writes ordered after m=0's P reads (same-wave DS order)
#pragma unroll
      for (int h2 = 0; h2 < 2; ++h2) {
        bf16x4 pa = *reinterpret_cast<const bf16x4*>(prd[2 * h2]);
        bf16x4 pb = *reinterpret_cast<const bf16x4*>(prd[2 * h2 + 1]);
        bf16x8 pf = __builtin_shufflevector(pa, pb, 0, 1, 2, 3, 4, 5, 6, 7);
#pragma unroll
        for (int j = 0; j < 4; ++j)
          O[m][j] = __builtin_amdgcn_mfma_f32_16x16x32_bf16(pf, vf[j][h2], O[m][j], 0, 0, 0);
      }
    }
    __builtin_amdgcn_s_barrier();   // all waves done reading buf[cur]; no drain
  }

  // epilogue: reduce psum over lq bits -> per-q total for this K-half;
  // store psum (lanes lq==0, consecutive rows -> coalesced) + raw O (bf16)
#pragma unroll
  for (int m = 0; m < 2; ++m) {
    float s = psum[m];
    s += __shfl_xor(s, 16, 64);
    s += __shfl_xor(s, 32, 64);
    int prow = q0 + w * 32 + m * 16 + lm;
    if (lq == 0) psZ[bh * 2048 + prow] = s;
#pragma unroll
    for (int r = 0; r < 4; ++r) {
      int row = q0 + w * 32 + m * 16 + lq * 4 + r;
      size_t base = ((size_t)b * 2048 + row) * 1024 + h * 64 + lm;
#pragma unroll
      for (int j = 0; j < 4; ++j)
        Op[base + j * 16] = f2bf(O[m][j][r]);
    }
  }
}

// ---------------- combine K-split partials + normalize -> bf16 ctx ----------
__global__ __launch_bounds__(256) void combine_norm(
    const u16* __restrict__ Oa, const u16* __restrict__ Ob,
    const float* __restrict__ psA, const float* __restrict__ psB,
    u16* __restrict__ ctx)
{
  size_t idx = ((size_t)blockIdx.x * 256 + threadIdx.x) * 8;   // over 4M elements
  int q = (int)(idx >> 10);          // b*2048 + l
  int c = (int)(idx & 1023);
  int b = q >> 11, l = q & 2047, h = c >> 6;
  int ql = (b * 16 + h) * 2048 + l;
  float s = psA[ql] + psB[ql];
  float inv = (s > 0.f) ? 1.0f / s : 0.f;   // all-masked row -> 0

  uint4 ua = *reinterpret_cast<const uint4*>(Oa + idx);
  uint4 ub = *reinterpret_cast<const uint4*>(Ob + idx);
  uint4 uo;
  const unsigned* pa = reinterpret_cast<const unsigned*>(&ua);
  const unsigned* pb = reinterpret_cast<const unsigned*>(&ub);
  unsigned* po = reinterpret_cast<unsigned*>(&uo);
#pragma unroll
  for (int i = 0; i < 4; ++i) {
    float alo = __uint_as_float(pa[i] << 16);
    float ahi = __uint_as_float(pa[i] & 0xFFFF0000u);
    float blo = __uint_as_float(pb[i] << 16);
    float bhi = __uint_as_float(pb[i] & 0xFFFF0000u);
    float olo = (alo + blo) * inv;
    float ohi = (ahi + bhi) * inv;
    po[i] = (unsigned)f2bf(olo) | ((unsigned)f2bf(ohi) << 16);
  }
  *reinterpret_cast<uint4*>(ctx + idx) = uo;
}

// ---------------- host ----------------
extern "C" void kernel_launch(void* const* d_in, const int* in_sizes, int n_in,
                              void* d_out, int out_size, void* d_ws, size_t ws_size,
                              hipStream_t stream) {
  const float* q  = (const float*)d_in[0];
  const float* k  = (const float*)d_in[1];
  const float* v  = (const float*)d_in[2];
  const int*   mk = (const int*)  d_in[3];
  const float* wq = (const float*)d_in[4];
  const float* wk = (const float*)d_in[5];
  const float* wv = (const float*)d_in[6];
  const float* wo = (const float*)d_in[7];
  const float* bo = (const float*)d_in[8];

  u16* ws16 = (u16*)d_ws;
  // element offsets (bf16): Xq=0 Xk=4M Xv=8M | Wq=12M Wk=13M Wv=14M Wo=15M
  // Qp=16M Kp=20M Vt=24M.
  // After proj: Xq/Xv/Wq..Wv are dead -> OpA=0..4M, OpB=8..12M,
  // psums (fp32) at element 12M (512 KB inside Wq..), ctx=4..8M (Xk alias).
  u16* Xq  = ws16;
  u16* Wq  = ws16 + 12 * MEG;
  u16* Wo  = ws16 + 15 * MEG;
  u16* Qp  = ws16 + 16 * MEG;
  u16* Kp  = ws16 + 20 * MEG;
  u16* Vt  = ws16 + 24 * MEG;
  u16* OpA = ws16;             // alias Xq
  u16* OpB = ws16 + 8 * MEG;   // alias Xv
  float* psAB = (float*)(ws16 + 12 * MEG);  // alias Wq (2 x 65536 floats)
  u16* ctx = ws16 + 4 * MEG;   // alias Xk

  cvt7<<<dim3(16384), dim3(256), 0, stream>>>(q, k, v, wq, wk, wv, wo, ws16);

  gemm_bt<4, true, false, true><<<dim3(8, 32, 3), dim3(256), 0, stream>>>(
      Xq, Wq, nullptr, (void*)Qp, Vt, 4096, 1024, 1024,
      (long)(4 * MEG), (long)MEG, (long)(4 * MEG));

  attn_kernel<<<dim3(16, 32, 2), dim3(256), 0, stream>>>(Qp, Kp, Vt, mk, OpA, psAB);

  combine_norm<<<dim3(2048), dim3(256), 0, stream>>>(OpA, OpB, psAB, psAB + 65536, ctx);

  gemm_bt<2, false, true, false><<<dim3(8, 64, 1), dim3(256), 0, stream>>>(
      ctx, Wo, bo, d_out, nullptr, 4096, 1024, 1024, 0, 0, 0);
}

// Round 11
// 218.367 us; speedup vs baseline: 1.4643x; 1.0628x over previous
//
#include <hip/hip_runtime.h>

typedef unsigned short u16;
typedef __bf16 bf16x8 __attribute__((ext_vector_type(8)));
typedef __bf16 bf16x4 __attribute__((ext_vector_type(4)));
typedef float floatx4 __attribute__((ext_vector_type(4)));
typedef u16 u16x4 __attribute__((ext_vector_type(4)));

#define MEG ((size_t)(1u << 20))

__device__ __forceinline__ u16 f2bf(float f) {
  unsigned int u = __float_as_uint(f);
  u += 0x7fffu + ((u >> 16) & 1u);   // round-to-nearest-even
  return (u16)(u >> 16);
}

// async global->LDS, 16B per lane; LDS dest = wave-uniform base + lane*16
__device__ __forceinline__ void load_lds16(const u16* g, u16* l) {
  __builtin_amdgcn_global_load_lds((const __attribute__((address_space(1))) unsigned int*)g,
                                   (__attribute__((address_space(3))) unsigned int*)l,
                                   16, 0, 0);
}

// ---------------- fp32 -> bf16 conversion of the 7 fp32 inputs ----------------
// layout (elements): [q 4M][k 4M][v 4M][Wq 1M][Wk 1M][Wv 1M][Wo 1M] = 16M
// 16 elems/thread (4 independent float4 loads) for memory-level parallelism.
__global__ __launch_bounds__(256) void cvt7(
    const float* __restrict__ s0, const float* __restrict__ s1,
    const float* __restrict__ s2, const float* __restrict__ s3,
    const float* __restrict__ s4, const float* __restrict__ s5,
    const float* __restrict__ s6, u16* __restrict__ dst)
{
  size_t e = ((size_t)blockIdx.x * 256 + threadIdx.x) * 16;
  unsigned m = (unsigned)(e >> 20);
  const float* s; size_t off;
  if (m < 4)       { s = s0; off = e; }
  else if (m < 8)  { s = s1; off = e - 4 * MEG; }
  else if (m < 12) { s = s2; off = e - 8 * MEG; }
  else if (m < 13) { s = s3; off = e - 12 * MEG; }
  else if (m < 14) { s = s4; off = e - 13 * MEG; }
  else if (m < 15) { s = s5; off = e - 14 * MEG; }
  else             { s = s6; off = e - 15 * MEG; }
  float4 f[4];
#pragma unroll
  for (int t = 0; t < 4; ++t)
    f[t] = *reinterpret_cast<const float4*>(s + off + t * 4);
#pragma unroll
  for (int t = 0; t < 4; ++t) {
    u16x4 o;
    o.x = f2bf(f[t].x); o.y = f2bf(f[t].y); o.z = f2bf(f[t].z); o.w = f2bf(f[t].w);
    *reinterpret_cast<u16x4*>(dst + e + t * 4) = o;
  }
}

// ---------------- generic C = A * B^T (+bias) bf16 MFMA GEMM, BK=64 ----------
// A: MxK bf16 row-major, B: NxK bf16 row-major, C: MxN (bf16 or fp32)
// Tile (IT*32) x 128; m-tile from blockIdx.X, n-tile from blockIdx.Y so that
// CONSECUTIVE dispatch ids share the same B (weight) tile -> B stays hot in
// each XCD's L2, A streams once (XCD-locality swizzle).
// xor-chunk-swizzled LDS (slot = c ^ (row&7)), conflict-free b128 frag reads.
// VT: blockIdx.z==2 writes the transposed-per-head layout Vt[bh][d][l] instead.
template<int IT, bool OUT_BF16, bool ADD_BIAS, bool VT>
__global__ __launch_bounds__(256) void gemm_bt(
    const u16* __restrict__ Abase, const u16* __restrict__ Bbase,
    const float* __restrict__ bias, void* __restrict__ Cbase,
    u16* __restrict__ VtB,
    int M, int N, int K, long zA, long zB, long zC)
{
  __shared__ __align__(16) u16 As[IT * 32 * 64];
  __shared__ __align__(16) u16 Bs[128 * 64];
  const int tid = threadIdx.x;
  const int w = tid >> 6, ln = tid & 63;
  const int lm = ln & 15, lq = ln >> 4;
  const int wm = w >> 1, wn = w & 1;
  const long m0 = (long)blockIdx.x * (IT * 32), n0 = (long)blockIdx.y * 128;
  const u16* A = Abase + (size_t)blockIdx.z * (size_t)zA;
  const u16* B = Bbase + (size_t)blockIdx.z * (size_t)zB;

  const int r0 = tid >> 3;
  const int kc = (tid & 7) ^ (r0 & 7);
  const u16* gA = A + (m0 + r0) * (long)K + kc * 8;
  const u16* gB = B + (n0 + r0) * (long)K + kc * 8;
  const long rstep = 32L * K;

  const int sl0 = (lq ^ (lm & 7)) * 8;
  const int sl1 = ((4 + lq) ^ (lm & 7)) * 8;
  const u16* ab0 = &As[(wm * (IT * 16) + lm) * 64 + sl0];
  const u16* ab1 = &As[(wm * (IT * 16) + lm) * 64 + sl1];
  const u16* bb0 = &Bs[(wn * 64 + lm) * 64 + sl0];
  const u16* bb1 = &Bs[(wn * 64 + lm) * 64 + sl1];

  const floatx4 z4 = {0.f, 0.f, 0.f, 0.f};
  floatx4 acc[IT][4];
#pragma unroll
  for (int i = 0; i < IT; ++i)
#pragma unroll
    for (int j = 0; j < 4; ++j) acc[i][j] = z4;

  for (int k0 = 0; k0 < K; k0 += 64) {
#pragma unroll
    for (int t = 0; t < IT; ++t)
      load_lds16(gA + t * rstep, &As[(t * 256 + w * 64) * 8]);
#pragma unroll
    for (int t = 0; t < 4; ++t)
      load_lds16(gB + t * rstep, &Bs[(t * 256 + w * 64) * 8]);
    gA += 64; gB += 64;
    __syncthreads();
    bf16x8 af[IT][2], bfr[4][2];
#pragma unroll
    for (int i = 0; i < IT; ++i) {
      af[i][0] = *reinterpret_cast<const bf16x8*>(ab0 + i * 1024);
      af[i][1] = *reinterpret_cast<const bf16x8*>(ab1 + i * 1024);
    }
#pragma unroll
    for (int j = 0; j < 4; ++j) {
      bfr[j][0] = *reinterpret_cast<const bf16x8*>(bb0 + j * 1024);
      bfr[j][1] = *reinterpret_cast<const bf16x8*>(bb1 + j * 1024);
    }
#pragma unroll
    for (int i = 0; i < IT; ++i)
#pragma unroll
      for (int j = 0; j < 4; ++j) {
        acc[i][j] = __builtin_amdgcn_mfma_f32_16x16x32_bf16(af[i][0], bfr[j][0], acc[i][j], 0, 0, 0);
        acc[i][j] = __builtin_amdgcn_mfma_f32_16x16x32_bf16(af[i][1], bfr[j][1], acc[i][j], 0, 0, 0);
      }
    __syncthreads();
  }

  if (VT && blockIdx.z == 2) {
#pragma unroll
    for (int i = 0; i < IT; ++i) {
      long row = m0 + wm * (IT * 16) + i * 16 + lq * 4;   // row = b*2048 + l
      int bq = (int)(row >> 11);
      int l  = (int)(row & 2047);
#pragma unroll
      for (int j = 0; j < 4; ++j) {
        long col = n0 + wn * 64 + j * 16 + lm;            // col = h*64 + d
        int hh = (int)(col >> 6), dd = (int)(col & 63);
        u16x4 o;
        o.x = f2bf(acc[i][j][0]); o.y = f2bf(acc[i][j][1]);
        o.z = f2bf(acc[i][j][2]); o.w = f2bf(acc[i][j][3]);
        *reinterpret_cast<u16x4*>(&VtB[((size_t)(bq * 16 + hh)) * 131072 +
                                       (size_t)dd * 2048 + l]) = o;
      }
    }
    return;
  }

#pragma unroll
  for (int i = 0; i < IT; ++i) {
    long row = m0 + wm * (IT * 16) + i * 16 + lq * 4;
#pragma unroll
    for (int j = 0; j < 4; ++j) {
      long col = n0 + wn * 64 + j * 16 + lm;
#pragma unroll
      for (int r = 0; r < 4; ++r) {
        float v = acc[i][j][r];
        if (ADD_BIAS) v += bias[col];
        size_t idx = (size_t)(row + r) * (size_t)N + (size_t)col;
        if (OUT_BF16) (((u16*)Cbase) + (size_t)blockIdx.z * (size_t)zC)[idx] = f2bf(v);
        else ((float*)Cbase)[idx] = v;
      }
    }
  }
}

// ---------------- flash attention, K-split=2 (R8 structure) ------------------
// grid (16 q-tiles of 128, 32 bh, 2 K-halves) = 1024 blocks, 4 waves,
// 32 q-rows/wave (2 subtiles of 16), K-tile 64, 16 iters per block.
// fp32 mask-bias table (no per-iter unpack). 36 KB LDS -> 4 blocks/CU.
// Writes UN-normalized O (bf16) + fp32 psum partials; combine_norm finishes.
__global__ __launch_bounds__(256, 4) void attn_kernel(
    const u16* __restrict__ Qp, const u16* __restrict__ Kp,
    const u16* __restrict__ Vt, const int* __restrict__ mask,
    u16* __restrict__ OpBase, float* __restrict__ psAB)
{
  __shared__ __align__(16) u16 Ks[64 * 64];       // 8 KB, slot = c ^ (key&7)
  __shared__ __align__(16) u16 Vts[64 * 64];      // 8 KB, slot = c ^ (d&7)
  __shared__ __align__(16) u16 Ps[4 * 32 * 64];   // 16 KB, per-wave, 2 subtiles
  __shared__ __align__(16) float mball[1024];     // 4 KB mask bias fp32 (0/-inf)

  const int tid = threadIdx.x;
  const int w = tid >> 6, ln = tid & 63;
  const int lm = ln & 15, lq = ln >> 4;
  const int bh = blockIdx.y, b = bh >> 4, h = bh & 15;
  const int q0 = blockIdx.x * 128;
  const int kz = blockIdx.z;

  const u16* Qh = Qp + (size_t)b * 2048 * 1024 + h * 64;
  const u16* Kh = Kp + (size_t)b * 2048 * 1024 + (size_t)kz * 1024 * 1024 + h * 64;
  const u16* Vth = Vt + (size_t)bh * 64 * 2048 + kz * 1024;
  u16* Op = OpBase + (size_t)kz * 8 * MEG;
  float* psZ = psAB + (size_t)kz * 65536;

  // mask bias staged once (first __syncthreads covers visibility)
  const int* mrowp = mask + b * 2048 + kz * 1024;
#pragma unroll
  for (int t = 0; t < 4; ++t) {
    int i = t * 256 + tid;
    mball[i] = (mrowp[i] != 0) ? 0.f : -__builtin_inff();
  }

  // persistent Q fragments (B-operand for S^T), 2 q-subtiles
  bf16x8 qf[2][2];
#pragma unroll
  for (int m = 0; m < 2; ++m) {
    int qrow = q0 + w * 32 + m * 16 + lm;
    qf[m][0] = *reinterpret_cast<const bf16x8*>(Qh + (size_t)qrow * 1024 + lq * 8);
    qf[m][1] = *reinterpret_cast<const bf16x8*>(Qh + (size_t)qrow * 1024 + 32 + lq * 8);
  }

  // loop-invariant LDS pointers
  const int sl0 = (lq ^ (lm & 7)) * 8;
  const int sl1 = ((4 + lq) ^ (lm & 7)) * 8;
  const u16* kb0 = &Ks[lm * 64 + sl0];
  const u16* kb1 = &Ks[lm * 64 + sl1];
  const u16* vb0 = &Vts[lm * 64 + sl0];
  const u16* vb1 = &Vts[lm * 64 + sl1];
  u16* Pw = &Ps[w * 2048];
  u16* pwr[4];
#pragma unroll
  for (int n = 0; n < 4; ++n) pwr[n] = &Pw[lm * 64 + (((4 * n + lq) ^ lm) * 4)];
  const u16* prd[4];
#pragma unroll
  for (int t = 0; t < 4; ++t)
    prd[t] = &Pw[lm * 64 + (((8 * (t >> 1) + 2 * lq + (t & 1)) ^ lm) * 4)];
  const float* mbi = mball + lq * 4;

  // staging source running pointers (row r0 = tid>>3, chunk kc = (tid&7)^(r0&7))
  const int r0 = tid >> 3;
  const int kc = (tid & 7) ^ (r0 & 7);
  const u16* gK0 = Kh + (size_t)r0 * 1024 + kc * 8;
  const u16* gK1 = gK0 + 32 * 1024;
  const u16* gV0 = Vth + (size_t)r0 * 2048 + kc * 8;
  const u16* gV1 = gV0 + 32 * 2048;

  const floatx4 z4 = {0.f, 0.f, 0.f, 0.f};
  floatx4 O[2][4];
#pragma unroll
  for (int m = 0; m < 2; ++m)
#pragma unroll
    for (int j = 0; j < 4; ++j) O[m][j] = z4;
  float psum[2] = {0.f, 0.f};
  const float SCL = 0.18033688011112042f;  // log2(e) / sqrt(64)

  for (int it = 0; it < 16; ++it) {
    load_lds16(gK0, &Ks[(w * 64) * 8]);
    load_lds16(gK1, &Ks[(256 + w * 64) * 8]);
    load_lds16(gV0, &Vts[(w * 64) * 8]);
    load_lds16(gV1, &Vts[(256 + w * 64) * 8]);
    gK0 += 64 * 1024; gK1 += 64 * 1024; gV0 += 64; gV1 += 64;
    __syncthreads();

    // shared fragments for both q-subtiles
    bf16x8 kf[4][2], vf[4][2];
#pragma unroll
    for (int n = 0; n < 4; ++n) {
      kf[n][0] = *reinterpret_cast<const bf16x8*>(kb0 + n * 1024);
      kf[n][1] = *reinterpret_cast<const bf16x8*>(kb1 + n * 1024);
    }
#pragma unroll
    for (int j = 0; j < 4; ++j) {
      vf[j][0] = *reinterpret_cast<const bf16x8*>(vb0 + j * 1024);
      vf[j][1] = *reinterpret_cast<const bf16x8*>(vb1 + j * 1024);
    }
    float4 mb4[4];
#pragma unroll
    for (int n = 0; n < 4; ++n)
      mb4[n] = *reinterpret_cast<const float4*>(mbi + n * 16);
    mbi += 64;

#pragma unroll
    for (int m = 0; m < 2; ++m) {
      // S^T = K_tile * Q^T : D[key_local = lq*4+r][q = lm]
      floatx4 S[4];
#pragma unroll
      for (int n = 0; n < 4; ++n) {
        S[n] = __builtin_amdgcn_mfma_f32_16x16x32_bf16(kf[n][0], qf[m][0], z4, 0, 0, 0);
        S[n] = __builtin_amdgcn_mfma_f32_16x16x32_bf16(kf[n][1], qf[m][1], S[n], 0, 0, 0);
      }

      // p = exp2(S*SCL + maskbias); raw v_exp; pack via +0x8000 + v_perm
#pragma unroll
      for (int n = 0; n < 4; ++n) {
        float p0 = __builtin_amdgcn_exp2f(fmaf(S[n][0], SCL, mb4[n].x));
        float p1 = __builtin_amdgcn_exp2f(fmaf(S[n][1], SCL, mb4[n].y));
        float p2 = __builtin_amdgcn_exp2f(fmaf(S[n][2], SCL, mb4[n].z));
        float p3 = __builtin_amdgcn_exp2f(fmaf(S[n][3], SCL, mb4[n].w));
        psum[m] += (p0 + p1) + (p2 + p3);
        unsigned u0 = __float_as_uint(p0) + 0x8000u;
        unsigned u1 = __float_as_uint(p1) + 0x8000u;
        unsigned u2 = __float_as_uint(p2) + 0x8000u;
        unsigned u3 = __float_as_uint(p3) + 0x8000u;
        uint2 pk;
        pk.x = __builtin_amdgcn_perm(u1, u0, 0x07060302u);
        pk.y = __builtin_amdgcn_perm(u3, u2, 0x07060302u);
        *reinterpret_cast<uint2*>(pwr[n] + m * 1024) = pk;
      }

      // O += P(16x64) * V(64x64); per-wave Ps, same-wave DS order -> no barrier
#pragma unroll
      for (int h2 = 0; h2 < 2; ++h2) {
        bf16x4 pa = *reinterpret_cast<const bf16x4*>(prd[2 * h2] + m * 1024);
        bf16x4 pb = *reinterpret_cast<const bf16x4*>(prd[2 * h2 + 1] + m * 1024);
        bf16x8 pf = __builtin_shufflevector(pa, pb, 0, 1, 2, 3, 4, 5, 6, 7);
#pragma unroll
        for (int j = 0; j < 4; ++j)
          O[m][j] = __builtin_amdgcn_mfma_f32_16x16x32_bf16(pf, vf[j][h2], O[m][j], 0, 0, 0);
      }
    }
    __syncthreads();
  }

  // epilogue: reduce psum over lq bits -> per-q total for this K-half;
  // store psum (lanes lq==0, consecutive rows -> coalesced) + raw O (bf16)
#pragma unroll
  for (int m = 0; m < 2; ++m) {
    float s = psum[m];
    s += __shfl_xor(s, 16, 64);
    s += __shfl_xor(s, 32, 64);
    int prow = q0 + w * 32 + m * 16 + lm;
    if (lq == 0) psZ[bh * 2048 + prow] = s;
#pragma unroll
    for (int r = 0; r < 4; ++r) {
      int row = q0 + w * 32 + m * 16 + lq * 4 + r;
      size_t base = ((size_t)b * 2048 + row) * 1024 + h * 64 + lm;
#pragma unroll
      for (int j = 0; j < 4; ++j)
        Op[base + j * 16] = f2bf(O[m][j][r]);
    }
  }
}

// ---------------- combine K-split partials + normalize -> bf16 ctx ----------
__global__ __launch_bounds__(256) void combine_norm(
    const u16* __restrict__ Oa, const u16* __restrict__ Ob,
    const float* __restrict__ psA, const float* __restrict__ psB,
    u16* __restrict__ ctx)
{
  size_t idx = ((size_t)blockIdx.x * 256 + threadIdx.x) * 8;   // over 4M elements
  int q = (int)(idx >> 10);          // b*2048 + l
  int c = (int)(idx & 1023);
  int b = q >> 11, l = q & 2047, h = c >> 6;
  int ql = (b * 16 + h) * 2048 + l;
  float s = psA[ql] + psB[ql];
  float inv = (s > 0.f) ? 1.0f / s : 0.f;   // all-masked row -> 0

  uint4 ua = *reinterpret_cast<const uint4*>(Oa + idx);
  uint4 ub = *reinterpret_cast<const uint4*>(Ob + idx);
  uint4 uo;
  const unsigned* pa = reinterpret_cast<const unsigned*>(&ua);
  const unsigned* pb = reinterpret_cast<const unsigned*>(&ub);
  unsigned* po = reinterpret_cast<unsigned*>(&uo);
#pragma unroll
  for (int i = 0; i < 4; ++i) {
    float alo = __uint_as_float(pa[i] << 16);
    float ahi = __uint_as_float(pa[i] & 0xFFFF0000u);
    float blo = __uint_as_float(pb[i] << 16);
    float bhi = __uint_as_float(pb[i] & 0xFFFF0000u);
    float olo = (alo + blo) * inv;
    float ohi = (ahi + bhi) * inv;
    po[i] = (unsigned)f2bf(olo) | ((unsigned)f2bf(ohi) << 16);
  }
  *reinterpret_cast<uint4*>(ctx + idx) = uo;
}

// ---------------- host ----------------
extern "C" void kernel_launch(void* const* d_in, const int* in_sizes, int n_in,
                              void* d_out, int out_size, void* d_ws, size_t ws_size,
                              hipStream_t stream) {
  const float* q  = (const float*)d_in[0];
  const float* k  = (const float*)d_in[1];
  const float* v  = (const float*)d_in[2];
  const int*   mk = (const int*)  d_in[3];
  const float* wq = (const float*)d_in[4];
  const float* wk = (const float*)d_in[5];
  const float* wv = (const float*)d_in[6];
  const float* wo = (const float*)d_in[7];
  const float* bo = (const float*)d_in[8];

  u16* ws16 = (u16*)d_ws;
  // element offsets (bf16): Xq=0 Xk=4M Xv=8M | Wq=12M Wk=13M Wv=14M Wo=15M
  // Qp=16M Kp=20M Vt=24M.
  // After proj: Xq/Xv/Wq..Wv are dead -> OpA=0..4M, OpB=8..12M,
  // psums (fp32) at element 12M (512 KB inside Wq..), ctx=4..8M (Xk alias).
  u16* Xq  = ws16;
  u16* Wq  = ws16 + 12 * MEG;
  u16* Wo  = ws16 + 15 * MEG;
  u16* Qp  = ws16 + 16 * MEG;
  u16* Kp  = ws16 + 20 * MEG;
  u16* Vt  = ws16 + 24 * MEG;
  u16* OpA = ws16;             // alias Xq
  u16* OpB = ws16 + 8 * MEG;   // alias Xv
  float* psAB = (float*)(ws16 + 12 * MEG);  // alias Wq (2 x 65536 floats)
  u16* ctx = ws16 + 4 * MEG;   // alias Xk

  cvt7<<<dim3(4096), dim3(256), 0, stream>>>(q, k, v, wq, wk, wv, wo, ws16);

  // grid: m-tiles on x (32), n-tiles on y (8) -> consecutive blocks share B tile
  gemm_bt<4, true, false, true><<<dim3(32, 8, 3), dim3(256), 0, stream>>>(
      Xq, Wq, nullptr, (void*)Qp, Vt, 4096, 1024, 1024,
      (long)(4 * MEG), (long)MEG, (long)(4 * MEG));

  attn_kernel<<<dim3(16, 32, 2), dim3(256), 0, stream>>>(Qp, Kp, Vt, mk, OpA, psAB);

  combine_norm<<<dim3(2048), dim3(256), 0, stream>>>(OpA, OpB, psAB, psAB + 65536, ctx);

  gemm_bt<2, false, true, false><<<dim3(64, 8, 1), dim3(256), 0, stream>>>(
      ctx, Wo, bo, d_out, nullptr, 4096, 1024, 1024, 0, 0, 0);
}

// Round 12
// 214.701 us; speedup vs baseline: 1.4893x; 1.0171x over previous
//
#include <hip/hip_runtime.h>

typedef unsigned short u16;
typedef __bf16 bf16x8 __attribute__((ext_vector_type(8)));
typedef __bf16 bf16x4 __attribute__((ext_vector_type(4)));
typedef float floatx4 __attribute__((ext_vector_type(4)));
typedef u16 u16x4 __attribute__((ext_vector_type(4)));

#define MEG ((size_t)(1u << 20))

__device__ __forceinline__ u16 f2bf(float f) {
  unsigned int u = __float_as_uint(f);
  u += 0x7fffu + ((u >> 16) & 1u);   // round-to-nearest-even
  return (u16)(u >> 16);
}

// async global->LDS, 16B per lane; LDS dest = wave-uniform base + lane*16
__device__ __forceinline__ void load_lds16(const u16* g, u16* l) {
  __builtin_amdgcn_global_load_lds((const __attribute__((address_space(1))) unsigned int*)g,
                                   (__attribute__((address_space(3))) unsigned int*)l,
                                   16, 0, 0);
}

// ---------------- fp32 -> bf16 conversion of the 7 fp32 inputs ----------------
// layout (elements): [q 4M][k 4M][v 4M][Wq 1M][Wk 1M][Wv 1M][Wo 1M] = 16M
// 16 elems/thread (4 independent float4 loads) for memory-level parallelism.
__global__ __launch_bounds__(256) void cvt7(
    const float* __restrict__ s0, const float* __restrict__ s1,
    const float* __restrict__ s2, const float* __restrict__ s3,
    const float* __restrict__ s4, const float* __restrict__ s5,
    const float* __restrict__ s6, u16* __restrict__ dst)
{
  size_t e = ((size_t)blockIdx.x * 256 + threadIdx.x) * 16;
  unsigned m = (unsigned)(e >> 20);
  const float* s; size_t off;
  if (m < 4)       { s = s0; off = e; }
  else if (m < 8)  { s = s1; off = e - 4 * MEG; }
  else if (m < 12) { s = s2; off = e - 8 * MEG; }
  else if (m < 13) { s = s3; off = e - 12 * MEG; }
  else if (m < 14) { s = s4; off = e - 13 * MEG; }
  else if (m < 15) { s = s5; off = e - 14 * MEG; }
  else             { s = s6; off = e - 15 * MEG; }
  float4 f[4];
#pragma unroll
  for (int t = 0; t < 4; ++t)
    f[t] = *reinterpret_cast<const float4*>(s + off + t * 4);
#pragma unroll
  for (int t = 0; t < 4; ++t) {
    u16x4 o;
    o.x = f2bf(f[t].x); o.y = f2bf(f[t].y); o.z = f2bf(f[t].z); o.w = f2bf(f[t].w);
    *reinterpret_cast<u16x4*>(dst + e + t * 4) = o;
  }
}

// ---------------- generic C = A * B^T bf16 MFMA GEMM, BK=64 (projections) ----
// A: MxK bf16 row-major, B: NxK bf16 row-major. Tile 128x128, 4 waves (2x2).
// m-tile on blockIdx.x so consecutive dispatch ids share the B (weight) tile.
// xor-chunk-swizzled LDS (slot = c ^ (row&7)), conflict-free b128 frag reads.
// blockIdx.z==2 writes the transposed-per-head layout Vt[bh][d][l] instead.
__global__ __launch_bounds__(256) void gemm_proj(
    const u16* __restrict__ Abase, const u16* __restrict__ Bbase,
    u16* __restrict__ Cbase, u16* __restrict__ VtB,
    int K, long zA, long zB, long zC)
{
  __shared__ __align__(16) u16 As[128 * 64];
  __shared__ __align__(16) u16 Bs[128 * 64];
  const int tid = threadIdx.x;
  const int w = tid >> 6, ln = tid & 63;
  const int lm = ln & 15, lq = ln >> 4;
  const int wm = w >> 1, wn = w & 1;
  const long m0 = (long)blockIdx.x * 128, n0 = (long)blockIdx.y * 128;
  const u16* A = Abase + (size_t)blockIdx.z * (size_t)zA;
  const u16* B = Bbase + (size_t)blockIdx.z * (size_t)zB;

  const int r0 = tid >> 3;
  const int kc = (tid & 7) ^ (r0 & 7);
  const u16* gA = A + (m0 + r0) * (long)K + kc * 8;
  const u16* gB = B + (n0 + r0) * (long)K + kc * 8;
  const long rstep = 32L * K;

  const int sl0 = (lq ^ (lm & 7)) * 8;
  const int sl1 = ((4 + lq) ^ (lm & 7)) * 8;
  const u16* ab0 = &As[(wm * 64 + lm) * 64 + sl0];
  const u16* ab1 = &As[(wm * 64 + lm) * 64 + sl1];
  const u16* bb0 = &Bs[(wn * 64 + lm) * 64 + sl0];
  const u16* bb1 = &Bs[(wn * 64 + lm) * 64 + sl1];

  const floatx4 z4 = {0.f, 0.f, 0.f, 0.f};
  floatx4 acc[4][4];
#pragma unroll
  for (int i = 0; i < 4; ++i)
#pragma unroll
    for (int j = 0; j < 4; ++j) acc[i][j] = z4;

  for (int k0 = 0; k0 < K; k0 += 64) {
#pragma unroll
    for (int t = 0; t < 4; ++t) {
      load_lds16(gA + t * rstep, &As[(t * 256 + w * 64) * 8]);
      load_lds16(gB + t * rstep, &Bs[(t * 256 + w * 64) * 8]);
    }
    gA += 64; gB += 64;
    __syncthreads();
    bf16x8 af[4][2], bfr[4][2];
#pragma unroll
    for (int i = 0; i < 4; ++i) {
      af[i][0] = *reinterpret_cast<const bf16x8*>(ab0 + i * 1024);
      af[i][1] = *reinterpret_cast<const bf16x8*>(ab1 + i * 1024);
    }
#pragma unroll
    for (int j = 0; j < 4; ++j) {
      bfr[j][0] = *reinterpret_cast<const bf16x8*>(bb0 + j * 1024);
      bfr[j][1] = *reinterpret_cast<const bf16x8*>(bb1 + j * 1024);
    }
#pragma unroll
    for (int i = 0; i < 4; ++i)
#pragma unroll
      for (int j = 0; j < 4; ++j) {
        acc[i][j] = __builtin_amdgcn_mfma_f32_16x16x32_bf16(af[i][0], bfr[j][0], acc[i][j], 0, 0, 0);
        acc[i][j] = __builtin_amdgcn_mfma_f32_16x16x32_bf16(af[i][1], bfr[j][1], acc[i][j], 0, 0, 0);
      }
    __syncthreads();
  }

  if (blockIdx.z == 2) {
    // write V^T per head: Vt[(b*16+h)][d][l]; r=0..3 -> consecutive l -> one b64
#pragma unroll
    for (int i = 0; i < 4; ++i) {
      long row = m0 + wm * 64 + i * 16 + lq * 4;          // row = b*2048 + l
      int bq = (int)(row >> 11);
      int l  = (int)(row & 2047);
#pragma unroll
      for (int j = 0; j < 4; ++j) {
        long col = n0 + wn * 64 + j * 16 + lm;            // col = h*64 + d
        int hh = (int)(col >> 6), dd = (int)(col & 63);
        u16x4 o;
        o.x = f2bf(acc[i][j][0]); o.y = f2bf(acc[i][j][1]);
        o.z = f2bf(acc[i][j][2]); o.w = f2bf(acc[i][j][3]);
        *reinterpret_cast<u16x4*>(&VtB[((size_t)(bq * 16 + hh)) * 131072 +
                                       (size_t)dd * 2048 + l]) = o;
      }
    }
    return;
  }

#pragma unroll
  for (int i = 0; i < 4; ++i) {
    long row = m0 + wm * 64 + i * 16 + lq * 4;
#pragma unroll
    for (int j = 0; j < 4; ++j) {
      long col = n0 + wn * 64 + j * 16 + lm;
#pragma unroll
      for (int r = 0; r < 4; ++r) {
        size_t idx = (size_t)(row + r) * 1024 + (size_t)col;
        (Cbase + (size_t)blockIdx.z * (size_t)zC)[idx] = f2bf(acc[i][j][r]);
      }
    }
  }
}

// ---------------- out GEMM with FUSED K-split combine + normalize ------------
// C = ((OpA+OpB)*inv) @ Wo^T + bo, fp32 out. A K-tile (64) == one head h=k0>>6,
// so inv = 1/(psA[ql]+psB[ql]) is uniform per (row, k-iter): computed inline.
// A staged manually (load 2x b128 -> combine -> ds_write at DMA-equivalent
// swizzled slot); B staged via DMA. Tile 64x128, grid (64 m, 8 n).
__global__ __launch_bounds__(256) void gemm_out_fused(
    const u16* __restrict__ OpA, const u16* __restrict__ OpB,
    const float* __restrict__ psA, const float* __restrict__ psB,
    const u16* __restrict__ Wo, const float* __restrict__ bias,
    float* __restrict__ Cout)
{
  __shared__ __align__(16) u16 As[64 * 64];
  __shared__ __align__(16) u16 Bs[128 * 64];
  const int tid = threadIdx.x;
  const int w = tid >> 6, ln = tid & 63;
  const int lm = ln & 15, lq = ln >> 4;
  const int wm = w >> 1, wn = w & 1;
  const long m0 = (long)blockIdx.x * 64, n0 = (long)blockIdx.y * 128;

  const int r0 = tid >> 3;
  const int kc = (tid & 7) ^ (r0 & 7);
  const u16* gB = Wo + (n0 + r0) * 1024 + kc * 8;
  const long rstep = 32L * 1024;

  const int sl0 = (lq ^ (lm & 7)) * 8;
  const int sl1 = ((4 + lq) ^ (lm & 7)) * 8;
  const u16* ab0 = &As[(wm * 32 + lm) * 64 + sl0];
  const u16* ab1 = &As[(wm * 32 + lm) * 64 + sl1];
  const u16* bb0 = &Bs[(wn * 64 + lm) * 64 + sl0];
  const u16* bb1 = &Bs[(wn * 64 + lm) * 64 + sl1];

  // A-staging row info (2 rows per thread, 32 apart)
  int rowg[2]; int qlb[2];
#pragma unroll
  for (int t = 0; t < 2; ++t) {
    rowg[t] = (int)m0 + r0 + t * 32;                 // b*2048 + l
    int b = rowg[t] >> 11, l = rowg[t] & 2047;
    qlb[t] = (b << 4) * 2048 + l;                    // + h*2048 added per iter
  }

  const floatx4 z4 = {0.f, 0.f, 0.f, 0.f};
  floatx4 acc[2][4];
#pragma unroll
  for (int i = 0; i < 2; ++i)
#pragma unroll
    for (int j = 0; j < 4; ++j) acc[i][j] = z4;

  for (int k0 = 0; k0 < 1024; k0 += 64) {
    // B via DMA
#pragma unroll
    for (int t = 0; t < 4; ++t)
      load_lds16(gB + t * rstep, &Bs[(t * 256 + w * 64) * 8]);
    gB += 64;
    // A manual: combine K-split partials + normalize, write swizzled slot
    const int h = k0 >> 6;
#pragma unroll
    for (int t = 0; t < 2; ++t) {
      int ql = qlb[t] + h * 2048;
      float s = psA[ql] + psB[ql];
      float inv = (s > 0.f) ? __builtin_amdgcn_rcpf(s) : 0.f;
      size_t idx = (size_t)rowg[t] * 1024 + k0 + kc * 8;
      uint4 ua = *reinterpret_cast<const uint4*>(OpA + idx);
      uint4 ub = *reinterpret_cast<const uint4*>(OpB + idx);
      uint4 uo;
      const unsigned* pa = reinterpret_cast<const unsigned*>(&ua);
      const unsigned* pb = reinterpret_cast<const unsigned*>(&ub);
      unsigned* po = reinterpret_cast<unsigned*>(&uo);
#pragma unroll
      for (int i = 0; i < 4; ++i) {
        float alo = __uint_as_float(pa[i] << 16);
        float ahi = __uint_as_float(pa[i] & 0xFFFF0000u);
        float blo = __uint_as_float(pb[i] << 16);
        float bhi = __uint_as_float(pb[i] & 0xFFFF0000u);
        float olo = (alo + blo) * inv;
        float ohi = (ahi + bhi) * inv;
        po[i] = (unsigned)f2bf(olo) | ((unsigned)f2bf(ohi) << 16);
      }
      *reinterpret_cast<uint4*>(&As[(size_t)(t * 256 + tid) * 8]) = uo;
    }
    __syncthreads();
    bf16x8 af[2][2], bfr[4][2];
#pragma unroll
    for (int i = 0; i < 2; ++i) {
      af[i][0] = *reinterpret_cast<const bf16x8*>(ab0 + i * 1024);
      af[i][1] = *reinterpret_cast<const bf16x8*>(ab1 + i * 1024);
    }
#pragma unroll
    for (int j = 0; j < 4; ++j) {
      bfr[j][0] = *reinterpret_cast<const bf16x8*>(bb0 + j * 1024);
      bfr[j][1] = *reinterpret_cast<const bf16x8*>(bb1 + j * 1024);
    }
#pragma unroll
    for (int i = 0; i < 2; ++i)
#pragma unroll
      for (int j = 0; j < 4; ++j) {
        acc[i][j] = __builtin_amdgcn_mfma_f32_16x16x32_bf16(af[i][0], bfr[j][0], acc[i][j], 0, 0, 0);
        acc[i][j] = __builtin_amdgcn_mfma_f32_16x16x32_bf16(af[i][1], bfr[j][1], acc[i][j], 0, 0, 0);
      }
    __syncthreads();
  }

#pragma unroll
  for (int i = 0; i < 2; ++i) {
    long row = m0 + wm * 32 + i * 16 + lq * 4;
#pragma unroll
    for (int j = 0; j < 4; ++j) {
      long col = n0 + wn * 64 + j * 16 + lm;
      float bv = bias[col];
#pragma unroll
      for (int r = 0; r < 4; ++r)
        Cout[(size_t)(row + r) * 1024 + (size_t)col] = acc[i][j][r] + bv;
    }
  }
}

// ---------------- flash attention, K-split=2 (R11 structure) -----------------
// grid (16 q-tiles of 128, 32 bh, 2 K-halves) = 1024 blocks, 4 waves,
// 32 q-rows/wave (2 subtiles of 16), K-tile 64, 16 iters per block.
// fp32 mask-bias table. 36 KB LDS -> 4 blocks/CU.
// Writes UN-normalized O (bf16) + fp32 psum partials; out GEMM fuses combine.
__global__ __launch_bounds__(256, 4) void attn_kernel(
    const u16* __restrict__ Qp, const u16* __restrict__ Kp,
    const u16* __restrict__ Vt, const int* __restrict__ mask,
    u16* __restrict__ OpBase, float* __restrict__ psAB)
{
  __shared__ __align__(16) u16 Ks[64 * 64];       // 8 KB, slot = c ^ (key&7)
  __shared__ __align__(16) u16 Vts[64 * 64];      // 8 KB, slot = c ^ (d&7)
  __shared__ __align__(16) u16 Ps[4 * 32 * 64];   // 16 KB, per-wave, 2 subtiles
  __shared__ __align__(16) float mball[1024];     // 4 KB mask bias fp32 (0/-inf)

  const int tid = threadIdx.x;
  const int w = tid >> 6, ln = tid & 63;
  const int lm = ln & 15, lq = ln >> 4;
  const int bh = blockIdx.y, b = bh >> 4, h = bh & 15;
  const int q0 = blockIdx.x * 128;
  const int kz = blockIdx.z;

  const u16* Qh = Qp + (size_t)b * 2048 * 1024 + h * 64;
  const u16* Kh = Kp + (size_t)b * 2048 * 1024 + (size_t)kz * 1024 * 1024 + h * 64;
  const u16* Vth = Vt + (size_t)bh * 64 * 2048 + kz * 1024;
  u16* Op = OpBase + (size_t)kz * 8 * MEG;
  float* psZ = psAB + (size_t)kz * 65536;

  // mask bias staged once (first __syncthreads covers visibility)
  const int* mrowp = mask + b * 2048 + kz * 1024;
#pragma unroll
  for (int t = 0; t < 4; ++t) {
    int i = t * 256 + tid;
    mball[i] = (mrowp[i] != 0) ? 0.f : -__builtin_inff();
  }

  // persistent Q fragments (B-operand for S^T), 2 q-subtiles
  bf16x8 qf[2][2];
#pragma unroll
  for (int m = 0; m < 2; ++m) {
    int qrow = q0 + w * 32 + m * 16 + lm;
    qf[m][0] = *reinterpret_cast<const bf16x8*>(Qh + (size_t)qrow * 1024 + lq * 8);
    qf[m][1] = *reinterpret_cast<const bf16x8*>(Qh + (size_t)qrow * 1024 + 32 + lq * 8);
  }

  // loop-invariant LDS pointers
  const int sl0 = (lq ^ (lm & 7)) * 8;
  const int sl1 = ((4 + lq) ^ (lm & 7)) * 8;
  const u16* kb0 = &Ks[lm * 64 + sl0];
  const u16* kb1 = &Ks[lm * 64 + sl1];
  const u16* vb0 = &Vts[lm * 64 + sl0];
  const u16* vb1 = &Vts[lm * 64 + sl1];
  u16* Pw = &Ps[w * 2048];
  u16* pwr[4];
#pragma unroll
  for (int n = 0; n < 4; ++n) pwr[n] = &Pw[lm * 64 + (((4 * n + lq) ^ lm) * 4)];
  const u16* prd[4];
#pragma unroll
  for (int t = 0; t < 4; ++t)
    prd[t] = &Pw[lm * 64 + (((8 * (t >> 1) + 2 * lq + (t & 1)) ^ lm) * 4)];
  const float* mbi = mball + lq * 4;

  // staging source running pointers (row r0 = tid>>3, chunk kc = (tid&7)^(r0&7))
  const int r0 = tid >> 3;
  const int kc = (tid & 7) ^ (r0 & 7);
  const u16* gK0 = Kh + (size_t)r0 * 1024 + kc * 8;
  const u16* gK1 = gK0 + 32 * 1024;
  const u16* gV0 = Vth + (size_t)r0 * 2048 + kc * 8;
  const u16* gV1 = gV0 + 32 * 2048;

  const floatx4 z4 = {0.f, 0.f, 0.f, 0.f};
  floatx4 O[2][4];
#pragma unroll
  for (int m = 0; m < 2; ++m)
#pragma unroll
    for (int j = 0; j < 4; ++j) O[m][j] = z4;
  float psum[2] = {0.f, 0.f};
  const float SCL = 0.18033688011112042f;  // log2(e) / sqrt(64)

  for (int it = 0; it < 16; ++it) {
    load_lds16(gK0, &Ks[(w * 64) * 8]);
    load_lds16(gK1, &Ks[(256 + w * 64) * 8]);
    load_lds16(gV0, &Vts[(w * 64) * 8]);
    load_lds16(gV1, &Vts[(256 + w * 64) * 8]);
    gK0 += 64 * 1024; gK1 += 64 * 1024; gV0 += 64; gV1 += 64;
    __syncthreads();

    // shared fragments for both q-subtiles
    bf16x8 kf[4][2], vf[4][2];
#pragma unroll
    for (int n = 0; n < 4; ++n) {
      kf[n][0] = *reinterpret_cast<const bf16x8*>(kb0 + n * 1024);
      kf[n][1] = *reinterpret_cast<const bf16x8*>(kb1 + n * 1024);
    }
#pragma unroll
    for (int j = 0; j < 4; ++j) {
      vf[j][0] = *reinterpret_cast<const bf16x8*>(vb0 + j * 1024);
      vf[j][1] = *reinterpret_cast<const bf16x8*>(vb1 + j * 1024);
    }
    float4 mb4[4];
#pragma unroll
    for (int n = 0; n < 4; ++n)
      mb4[n] = *reinterpret_cast<const float4*>(mbi + n * 16);
    mbi += 64;

#pragma unroll
    for (int m = 0; m < 2; ++m) {
      // S^T = K_tile * Q^T : D[key_local = lq*4+r][q = lm]
      floatx4 S[4];
#pragma unroll
      for (int n = 0; n < 4; ++n) {
        S[n] = __builtin_amdgcn_mfma_f32_16x16x32_bf16(kf[n][0], qf[m][0], z4, 0, 0, 0);
        S[n] = __builtin_amdgcn_mfma_f32_16x16x32_bf16(kf[n][1], qf[m][1], S[n], 0, 0, 0);
      }

      // p = exp2(S*SCL + maskbias); raw v_exp; pack via +0x8000 + v_perm
#pragma unroll
      for (int n = 0; n < 4; ++n) {
        float p0 = __builtin_amdgcn_exp2f(fmaf(S[n][0], SCL, mb4[n].x));
        float p1 = __builtin_amdgcn_exp2f(fmaf(S[n][1], SCL, mb4[n].y));
        float p2 = __builtin_amdgcn_exp2f(fmaf(S[n][2], SCL, mb4[n].z));
        float p3 = __builtin_amdgcn_exp2f(fmaf(S[n][3], SCL, mb4[n].w));
        psum[m] += (p0 + p1) + (p2 + p3);
        unsigned u0 = __float_as_uint(p0) + 0x8000u;
        unsigned u1 = __float_as_uint(p1) + 0x8000u;
        unsigned u2 = __float_as_uint(p2) + 0x8000u;
        unsigned u3 = __float_as_uint(p3) + 0x8000u;
        uint2 pk;
        pk.x = __builtin_amdgcn_perm(u1, u0, 0x07060302u);
        pk.y = __builtin_amdgcn_perm(u3, u2, 0x07060302u);
        *reinterpret_cast<uint2*>(pwr[n] + m * 1024) = pk;
      }

      // O += P(16x64) * V(64x64); per-wave Ps, same-wave DS order -> no barrier
#pragma unroll
      for (int h2 = 0; h2 < 2; ++h2) {
        bf16x4 pa = *reinterpret_cast<const bf16x4*>(prd[2 * h2] + m * 1024);
        bf16x4 pb = *reinterpret_cast<const bf16x4*>(prd[2 * h2 + 1] + m * 1024);
        bf16x8 pf = __builtin_shufflevector(pa, pb, 0, 1, 2, 3, 4, 5, 6, 7);
#pragma unroll
        for (int j = 0; j < 4; ++j)
          O[m][j] = __builtin_amdgcn_mfma_f32_16x16x32_bf16(pf, vf[j][h2], O[m][j], 0, 0, 0);
      }
    }
    __syncthreads();
  }

  // epilogue: reduce psum over lq bits -> per-q total for this K-half;
  // store psum (lanes lq==0, consecutive rows -> coalesced) + raw O (bf16)
#pragma unroll
  for (int m = 0; m < 2; ++m) {
    float s = psum[m];
    s += __shfl_xor(s, 16, 64);
    s += __shfl_xor(s, 32, 64);
    int prow = q0 + w * 32 + m * 16 + lm;
    if (lq == 0) psZ[bh * 2048 + prow] = s;
#pragma unroll
    for (int r = 0; r < 4; ++r) {
      int row = q0 + w * 32 + m * 16 + lq * 4 + r;
      size_t base = ((size_t)b * 2048 + row) * 1024 + h * 64 + lm;
#pragma unroll
      for (int j = 0; j < 4; ++j)
        Op[base + j * 16] = f2bf(O[m][j][r]);
    }
  }
}

// ---------------- host ----------------
extern "C" void kernel_launch(void* const* d_in, const int* in_sizes, int n_in,
                              void* d_out, int out_size, void* d_ws, size_t ws_size,
                              hipStream_t stream) {
  const float* q  = (const float*)d_in[0];
  const float* k  = (const float*)d_in[1];
  const float* v  = (const float*)d_in[2];
  const int*   mk = (const int*)  d_in[3];
  const float* wq = (const float*)d_in[4];
  const float* wk = (const float*)d_in[5];
  const float* wv = (const float*)d_in[6];
  const float* wo = (const float*)d_in[7];
  const float* bo = (const float*)d_in[8];

  u16* ws16 = (u16*)d_ws;
  // element offsets (bf16): Xq=0 Xk=4M Xv=8M | Wq=12M Wk=13M Wv=14M Wo=15M
  // Qp=16M Kp=20M Vt=24M.
  // After proj: Xq/Xv/Wq..Wv dead -> OpA=0..4M, OpB=8..12M,
  // psums (fp32) at element 12M (512 KB inside dead Wq).
  u16* Xq  = ws16;
  u16* Wq  = ws16 + 12 * MEG;
  u16* Wo  = ws16 + 15 * MEG;
  u16* Qp  = ws16 + 16 * MEG;
  u16* Kp  = ws16 + 20 * MEG;
  u16* Vt  = ws16 + 24 * MEG;
  u16* OpA = ws16;             // alias Xq
  u16* OpB = ws16 + 8 * MEG;   // alias Xv
  float* psAB = (float*)(ws16 + 12 * MEG);  // alias Wq (2 x 65536 floats)

  cvt7<<<dim3(4096), dim3(256), 0, stream>>>(q, k, v, wq, wk, wv, wo, ws16);

  // m-tiles on x (32), n-tiles on y (8): consecutive blocks share the B tile
  gemm_proj<<<dim3(32, 8, 3), dim3(256), 0, stream>>>(
      Xq, Wq, Qp, Vt, 1024, (long)(4 * MEG), (long)MEG, (long)(4 * MEG));

  attn_kernel<<<dim3(16, 32, 2), dim3(256), 0, stream>>>(Qp, Kp, Vt, mk, OpA, psAB);

  gemm_out_fused<<<dim3(64, 8), dim3(256), 0, stream>>>(
      OpA, OpB, psAB, psAB + 65536, Wo, bo, (float*)d_out);
}